// Round 6
// baseline (5213.611 us; speedup 1.0000x reference)
//
#include <hip/hip_runtime.h>
#include <stdint.h>

// ---------------- problem constants ----------------
#define B_   32
#define T_   256
#define H_   256      // per-direction hidden
#define DB_  768      // input dim
#define DL_  512      // 2*H

// ---------------- workspace layout (bytes) ----------------
#define OFF_DTYPE 0u                          // int: 1 = inputs bf16, 0 = f32
#define OFF_XZ    69632u                      // swizzled xz, per-dir stride 8M elems (16 MB)
#define XZ_DIR_ELEMS 8388608u
#define NEED_CONC (OFF_XZ + 2u*16777216u + 8388608u)
// ---- aliased into the xz region (xz dead after rec) ----
#define OFF_CTX   OFF_XZ                      // context [32][256][512] bf16 = 8 MB
#define OFF_WATT  (OFF_XZ + 8388608u)         // attn weights [32][256][256] bf16 = 4 MB
#define OFF_SQ    (OFF_XZ + 12582912u)        // [8192][10] f32
#define OFF_SK    (OFF_SQ + 327680u)          // [8192][10] f32

typedef __attribute__((ext_vector_type(8))) short bf16x8;
typedef __attribute__((ext_vector_type(4))) float f32x4;
typedef unsigned short ushort_t;

__device__ __forceinline__ float b2f(ushort_t u){ union{float f; uint32_t i;} v; v.i=((uint32_t)u)<<16; return v.f; }
__device__ __forceinline__ ushort_t f2b(float f){
  union{float ff; uint32_t i;} v; v.ff=f;
  uint32_t r = v.i + 0x7fffu + ((v.i>>16)&1u);
  return (ushort_t)(r>>16);
}
__device__ __forceinline__ float sig_f(float x){ return 1.f/(1.f+__expf(-x)); }
__device__ __forceinline__ float tanh_f(float x){ return 1.f - 2.f/(1.f+__expf(2.f*x)); }

__device__ __forceinline__ bf16x8 load8(const ushort_t* p, size_t idx, int isbf){
  if (isbf) return *(const bf16x8*)(p + idx);
  const float* f = (const float*)p;
  bf16x8 r;
  #pragma unroll
  for (int i=0;i<8;++i) r[i] = (short)f2b(f[idx+i]);
  return r;
}
__device__ __forceinline__ float loadS(const ushort_t* p, size_t idx, int isbf){
  return isbf ? b2f(p[idx]) : ((const float*)p)[idx];
}

// =====================================================================
// dtype probe (R3-verified): votes f32 vs bf16 from exponent stats.
// =====================================================================
__global__ void detect_k(const uint32_t* __restrict__ x, char* __restrict__ ws){
  __shared__ int cnt;
  if (threadIdx.x == 0) cnt = 0;
  __syncthreads();
  int local = 0;
  #pragma unroll
  for (int i=0;i<4;++i){
    uint32_t w = x[threadIdx.x*4 + i];
    uint32_t lo = w & 0xFFFFu;
    int e = (int)((lo >> 7) & 0xFFu);
    if (e >= 118 && e <= 130) local++;
  }
  atomicAdd(&cnt, local);
  __syncthreads();
  if (threadIdx.x == 0) *(int*)(ws + OFF_DTYPE) = (cnt > 512) ? 1 : 0;
}

// =====================================================================
// Generic 128x128-tile bf16 MFMA GEMM (unchanged, R4-R8-verified).
// =====================================================================
template<int MODE>
__global__ __launch_bounds__(256,2) void gemm_k(
    const ushort_t* __restrict__ A0, const ushort_t* __restrict__ A2,
    const ushort_t* __restrict__ Bm, const ushort_t* __restrict__ bias,
    ushort_t* __restrict__ Cout, char* __restrict__ ws,
    int lda, int ldb, int K, int dir, int aIn, int bIn,
    long aOffZ, long bOffZ, long cOffZ)
{
  __shared__ ushort_t As[8192];
  __shared__ ushort_t Bs[8192];
  const int dtf = *(const int*)(ws + OFF_DTYPE);
  const int aBF = aIn ? dtf : 1;
  const int bBF = bIn ? dtf : 1;
  const int tid = threadIdx.x;
  const int l  = tid & 63, wv = tid >> 6;
  const int lc = l & 15,  lh = l >> 4;
  const int m0 = blockIdx.x * 128, n0 = blockIdx.y * 128;
  const int z  = blockIdx.z;
  const ushort_t* Abase = A0 + (size_t)z * aOffZ;
  const ushort_t* Bbase = Bm + (size_t)z * bOffZ;
  const int srow = tid >> 3;
  const int sch  = tid & 7;

  f32x4 acc[4][4];
  #pragma unroll
  for (int i=0;i<4;++i)
    #pragma unroll
    for (int j=0;j<4;++j) acc[i][j] = (f32x4){0.f,0.f,0.f,0.f};

  bf16x8 ra[4], rb[4];
  #pragma unroll
  for (int p=0;p<4;++p){
    int row = p*32 + srow;
    int kk  = (sch ^ (row & 7)) * 8;
    ra[p] = load8(Abase, (size_t)(m0+row)*lda + kk, aBF);
    if (MODE==3){
      int q = p*256 + tid, kr = q>>4, c = q&15;
      rb[p] = load8(Bbase, (size_t)kr*ldb + n0 + c*8, 1);
    } else {
      rb[p] = load8(Bbase, (size_t)(n0+row)*ldb + kk, bBF);
    }
  }

  const int mo = (wv&1)*64, no = (wv>>1)*64;

  for (int k0 = 0; k0 < K; k0 += 64) {
    #pragma unroll
    for (int p=0;p<4;++p){
      int row = p*32 + srow;
      *(bf16x8*)(&As[row*64 + sch*8]) = ra[p];
      if (MODE==3){
        int q = p*256 + tid, kr = q>>4, c = q&15;
        *(bf16x8*)(&Bs[kr*128 + c*8]) = rb[p];
      } else {
        *(bf16x8*)(&Bs[row*64 + sch*8]) = rb[p];
      }
    }
    __syncthreads();
    int k1 = k0 + 64;
    if (k1 < K) {
      #pragma unroll
      for (int p=0;p<4;++p){
        int row = p*32 + srow;
        int kk  = k1 + (sch ^ (row & 7)) * 8;
        if (MODE==2 && k1 >= 512)
          ra[p] = load8(A2, (size_t)(m0+row)*512 + (kk - 512), 1);
        else
          ra[p] = load8(Abase, (size_t)(m0+row)*lda + kk, aBF);
        if (MODE==3){
          int q = p*256 + tid, kr = q>>4, c = q&15;
          rb[p] = load8(Bbase, (size_t)(k1+kr)*ldb + n0 + c*8, 1);
        } else {
          rb[p] = load8(Bbase, (size_t)(n0+row)*ldb + kk, bBF);
        }
      }
    }
    #pragma unroll
    for (int kc=0;kc<2;++kc){
      bf16x8 af[4], bfv[4];
      #pragma unroll
      for (int it=0;it<4;++it){
        int m = mo + it*16 + lc;
        int gc = kc*4 + lh;
        af[it]  = *(const bf16x8*)(&As[m*64 + ((gc ^ (m&7))*8)]);
        int n = no + it*16 + lc;
        if (MODE==3){
          #pragma unroll
          for (int j=0;j<8;++j) bfv[it][j] = (short)Bs[(kc*32 + lh*8 + j)*128 + n];
        } else {
          bfv[it] = *(const bf16x8*)(&Bs[n*64 + ((gc ^ (n&7))*8)]);
        }
      }
      #pragma unroll
      for (int mt=0;mt<4;++mt)
        #pragma unroll
        for (int nt=0;nt<4;++nt)
          acc[mt][nt] = __builtin_amdgcn_mfma_f32_16x16x32_bf16(af[mt], bfv[nt], acc[mt][nt], 0,0,0);
    }
    __syncthreads();
  }

  ushort_t* xzsw = (ushort_t*)(ws + OFF_XZ);
  #pragma unroll
  for (int mt=0;mt<4;++mt){
    #pragma unroll
    for (int nt=0;nt<4;++nt){
      #pragma unroll
      for (int r=0;r<4;++r){
        int m = m0 + mo + mt*16 + lh*4 + r;
        int n = n0 + no + nt*16 + lc;
        float v = acc[mt][nt][r];
        if (MODE==0){
          v += loadS(bias, n, bBF);
          int b = m >> 8, t = m & 255;
          int ts = dir ? (255 - t) : t;
          int q = n >> 8, jm = n & 255;
          int w = jm >> 6, jj = jm & 63, wvv = jj >> 4, colj = jj & 15;
          int lane = ((b >> 2) & 3)*16 + colj;
          int idx  = (b >> 4)*16 + q*4 + (b & 3);
          size_t e = (((size_t)(w*4 + wvv)*256 + ts)*2048) + (size_t)lane*32 + idx;
          xzsw[e + (size_t)cOffZ] = f2b(v);
        } else if (MODE==3){
          Cout[(size_t)z*cOffZ + (size_t)m*DL_ + n] = f2b(v);
        } else {
          v += loadS(bias, n, bBF);
          if (dtf) Cout[(size_t)m*DL_ + n] = f2b(v);
          else     ((float*)Cout)[(size_t)m*DL_ + n] = v;
        }
      }
    }
  }
}

// =====================================================================
// BiLSTM recurrence, v11 — ZERO inter-block communication.
//   R0/R3/R5 proved: any cross-block handoff costs ~4us/step through
//   LLC (protocol-invariant); multiplexing chains on one block cannot
//   beat 256*L. v11 removes the handoff: one block per (dir x
//   batch-half). Batch chains are independent -> blocks independent.
//   Each block: 16 batches x all 256 hidden units; h(t-1) handoff via
//   LDS + __syncthreads (~0.1us). Weights (512KB/dir) partitioned per
//   wave (w owns units [64w,64w+64), all 4 gate bands):
//     kc 4..7 -> VGPR-resident B-frags (64 frags, 256 regs/lane)
//     kc 2..3 -> LDS (32 frags/wave, 128KB/block)
//     kc 0..1 -> streamed from L2 each step (32 frags, latency hidden
//               under resident MFMAs; weights L2-resident after t=0)
//   All fragment layouts / xz swizzle / cell math / hist layout are
//   byte-identical to the R0-proven kernel. 2 barriers/step. No
//   sentinels, no polls, no fences. Deadlock structurally impossible.
// =====================================================================
__global__ __launch_bounds__(256,1) void rec_k(
    const ushort_t* __restrict__ Whh_f, const ushort_t* __restrict__ Whh_b,
    char* __restrict__ ws, ushort_t* __restrict__ hist,
    int dParam, long xzDirStride, int concMode)
{
  __shared__ ushort_t sm[69632];   // 128KB weights (kc2..3) + 8KB h = 136KB
  const int bid = (int)blockIdx.x;
  const int d  = concMode ? (bid >> 1) : dParam;
  const int mh = bid & 1;          // batch half: batches [16*mh, 16*mh+16)
  const int tid = threadIdx.x;
  const int w = tid >> 6, l = tid & 63;
  const int lc = l & 15, lh = l >> 4;
  const int dtf = *(const int*)(ws + OFF_DTYPE);

  const ushort_t* xz = (const ushort_t*)(ws + OFF_XZ) + (size_t)d * xzDirStride;
  const ushort_t* Whh = d ? Whh_b : Whh_f;

  // ---- stage weights: kc2..3 -> LDS, kc4..7 -> VGPR-resident frags ----
  bf16x8 wreg[64];
  #pragma unroll
  for (int kc=2;kc<8;++kc){
    #pragma unroll
    for (int gt=0;gt<4;++gt){
      #pragma unroll
      for (int nh=0;nh<4;++nh){
        int row = gt*256 + w*64 + nh*16 + lc;
        bf16x8 v = load8(Whh, (size_t)row*256 + kc*32 + lh*8, dtf);
        if (kc < 4)
          *(bf16x8*)(&sm[w*16384 + ((kc-2)*16 + gt*4 + nh)*512 + l*8]) = v;
        else
          wreg[(kc-4)*16 + gt*4 + nh] = v;
      }
    }
  }
  __syncthreads();

  ushort_t* hs = &sm[65536];            // h(t) bf16 [16 local batches][256 units]
  uint32_t* histw = (uint32_t*)hist;

  float cst[16];
  #pragma unroll
  for (int i=0;i<16;++i) cst[i] = 0.f;

  for (int t=0; t<T_; ++t){
    const int ts = d ? (255 - t) : t;

    // issue xz loads early (consumed after BAR1 in cell phase)
    bf16x8 xr[4][2];
    #pragma unroll
    for (int nh=0;nh<4;++nh){
      size_t e = ((size_t)((w*4+nh)*256 + t))*2048 + (size_t)l*32 + (size_t)mh*16;
      xr[nh][0] = *(const bf16x8*)(xz + e);
      xr[nh][1] = *(const bf16x8*)(xz + e + 8);
    }

    f32x4 acc[4][4];
    #pragma unroll
    for (int gt=0;gt<4;++gt)
      #pragma unroll
      for (int nh=0;nh<4;++nh) acc[gt][nh] = (f32x4){0.f,0.f,0.f,0.f};

    if (t > 0){
      // stream kc0 weight frags (L2-resident)
      bf16x8 s0[16];
      #pragma unroll
      for (int gt=0;gt<4;++gt)
        #pragma unroll
        for (int nh=0;nh<4;++nh)
          s0[gt*4+nh] = load8(Whh, (size_t)(gt*256 + w*64 + nh*16 + lc)*256 + lh*8, dtf);

      // resident kc4..7
      #pragma unroll
      for (int kc=4;kc<8;++kc){
        bf16x8 a = *(const bf16x8*)(&hs[lc*256 + kc*32 + lh*8]);
        #pragma unroll
        for (int gt=0;gt<4;++gt)
          #pragma unroll
          for (int nh=0;nh<4;++nh)
            acc[gt][nh] = __builtin_amdgcn_mfma_f32_16x16x32_bf16(a, wreg[(kc-4)*16 + gt*4 + nh], acc[gt][nh], 0,0,0);
      }
      // stream kc1 frags (issued while kc2..3 MFMAs run)
      bf16x8 s1[16];
      #pragma unroll
      for (int gt=0;gt<4;++gt)
        #pragma unroll
        for (int nh=0;nh<4;++nh)
          s1[gt*4+nh] = load8(Whh, (size_t)(gt*256 + w*64 + nh*16 + lc)*256 + 32 + lh*8, dtf);

      // LDS kc2..3
      #pragma unroll
      for (int kc=2;kc<4;++kc){
        bf16x8 a = *(const bf16x8*)(&hs[lc*256 + kc*32 + lh*8]);
        #pragma unroll
        for (int gt=0;gt<4;++gt)
          #pragma unroll
          for (int nh=0;nh<4;++nh){
            bf16x8 bf = *(const bf16x8*)(&sm[w*16384 + ((kc-2)*16 + gt*4 + nh)*512 + l*8]);
            acc[gt][nh] = __builtin_amdgcn_mfma_f32_16x16x32_bf16(a, bf, acc[gt][nh], 0,0,0);
          }
      }
      // streamed kc0, kc1
      {
        bf16x8 a0 = *(const bf16x8*)(&hs[lc*256 + 0*32 + lh*8]);
        #pragma unroll
        for (int gt=0;gt<4;++gt)
          #pragma unroll
          for (int nh=0;nh<4;++nh)
            acc[gt][nh] = __builtin_amdgcn_mfma_f32_16x16x32_bf16(a0, s0[gt*4+nh], acc[gt][nh], 0,0,0);
        bf16x8 a1 = *(const bf16x8*)(&hs[lc*256 + 1*32 + lh*8]);
        #pragma unroll
        for (int gt=0;gt<4;++gt)
          #pragma unroll
          for (int nh=0;nh<4;++nh)
            acc[gt][nh] = __builtin_amdgcn_mfma_f32_16x16x32_bf16(a1, s1[gt*4+nh], acc[gt][nh], 0,0,0);
      }
    }
    __syncthreads();   // BAR1: all reads of h(t-1) complete

    // ---- cell phase: writes h(t) to LDS + hist ----
    #pragma unroll
    for (int nh=0;nh<4;++nh){
      #pragma unroll
      for (int r=0;r<4;++r){
        float zi = acc[0][nh][r] + b2f((ushort_t)xr[nh][0][r]);
        float zf = acc[1][nh][r] + b2f((ushort_t)xr[nh][0][4+r]);
        float zg = acc[2][nh][r] + b2f((ushort_t)xr[nh][1][r]);
        float zo = acc[3][nh][r] + b2f((ushort_t)xr[nh][1][4+r]);
        float ig = sig_f(zi), fg = sig_f(zf), gg = tanh_f(zg), og = sig_f(zo);
        float c = fg * cst[nh*4+r] + ig * gg;
        cst[nh*4+r] = c;
        float h = og * tanh_f(c);
        ushort_t h16 = f2b(h);
        uint32_t mine = (uint32_t)h16;
        uint32_t partner = (uint32_t)__shfl_xor((int)mine, 1);
        if ((lc & 1) == 0){
          uint32_t packed = mine | (partner << 16);
          int u  = w*64 + nh*16 + lc;     // even unit
          int lb = lh*4 + r;              // local batch 0..15
          int gb = mh*16 + lb;            // global batch
          *(uint32_t*)(&hs[lb*256 + u]) = packed;
          histw[(((size_t)(gb*256 + ts))*512 + (size_t)(d*256 + u)) >> 1] = packed;
        }
      }
    }
    __syncthreads();   // BAR2: h(t) visible to all waves for step t+1
  }
}

// =====================================================================
// C1: sq[m][x] = h[m]·W1[x][0:512], sk[m][x] = h[m]·W1[x][512:1024]
// =====================================================================
__global__ __launch_bounds__(256) void c1_k(char* __restrict__ ws, const ushort_t* __restrict__ W1,
                                            const ushort_t* __restrict__ hist)
{
  float* sq = (float*)(ws + OFF_SQ);
  float* sk = (float*)(ws + OFF_SK);
  const int dtf = *(const int*)(ws + OFF_DTYPE);
  int tid = threadIdx.x; int wv = tid>>6, l = tid&63;
  int row = blockIdx.x*4 + wv;
  bf16x8 hv = *(const bf16x8*)(hist + (size_t)row*512 + l*8);
  float hf[8];
  #pragma unroll
  for (int i=0;i<8;++i) hf[i] = b2f((ushort_t)hv[i]);
  #pragma unroll
  for (int x=0;x<10;++x){
    bf16x8 qv = load8(W1, (size_t)x*1024 + l*8, dtf);
    bf16x8 kv = load8(W1, (size_t)x*1024 + 512 + l*8, dtf);
    float pq=0.f, pk=0.f;
    #pragma unroll
    for (int i=0;i<8;++i){ pq += hf[i]*b2f((ushort_t)qv[i]); pk += hf[i]*b2f((ushort_t)kv[i]); }
    #pragma unroll
    for (int off=32; off>0; off>>=1){ pq += __shfl_xor(pq, off, 64); pk += __shfl_xor(pk, off, 64); }
    if (l == 0){ sq[row*10 + x] = pq; sk[row*10 + x] = pk; }
  }
}

// =====================================================================
// C2: a = sum_x tanh(sq+sk)*W2[x]; masked softmax -> bf16 watt
// =====================================================================
__global__ __launch_bounds__(256) void c2_k(char* __restrict__ ws, const ushort_t* __restrict__ W2,
                                            const ushort_t* __restrict__ mask)
{
  const float* sq = (const float*)(ws + OFF_SQ);
  const float* sk = (const float*)(ws + OFF_SK);
  ushort_t* watt = (ushort_t*)(ws + OFF_WATT);
  const int dtf = *(const int*)(ws + OFF_DTYPE);
  int tid = threadIdx.x; int wv = tid>>6, l = tid&63;
  int bq = blockIdx.x*4 + wv;
  int b  = bq >> 8;
  float sqv[10], w2v[10];
  #pragma unroll
  for (int x=0;x<10;++x){ sqv[x] = sq[(size_t)bq*10+x]; w2v[x] = loadS(W2, x, dtf); }
  float a[4];
  #pragma unroll
  for (int kk=0;kk<4;++kk){
    int k = kk*64 + l;
    const float* skp = sk + ((size_t)b*256 + k)*10;
    float s = 0.f;
    #pragma unroll
    for (int x=0;x<10;++x) s += tanh_f(sqv[x] + skp[x]) * w2v[x];
    float mval = loadS(mask, (size_t)b*256 + k, dtf);
    a[kk] = (mval == 0.f) ? -1e30f : s;
  }
  float mx = fmaxf(fmaxf(a[0],a[1]), fmaxf(a[2],a[3]));
  #pragma unroll
  for (int off=32; off>0; off>>=1) mx = fmaxf(mx, __shfl_xor(mx, off, 64));
  float e[4], ssum=0.f;
  #pragma unroll
  for (int kk=0;kk<4;++kk){ e[kk] = __expf(a[kk]-mx); ssum += e[kk]; }
  #pragma unroll
  for (int off=32; off>0; off>>=1) ssum += __shfl_xor(ssum, off, 64);
  float inv = 1.f/ssum;
  #pragma unroll
  for (int kk=0;kk<4;++kk) watt[(size_t)bq*256 + kk*64 + l] = f2b(e[kk]*inv);
}

// =====================================================================
extern "C" void kernel_launch(void* const* d_in, const int* in_sizes, int n_in,
                              void* d_out, int out_size, void* d_ws, size_t ws_size,
                              hipStream_t stream)
{
  const ushort_t* x     = (const ushort_t*)d_in[0];
  const ushort_t* mask  = (const ushort_t*)d_in[1];
  const ushort_t* Wih_f = (const ushort_t*)d_in[2];
  const ushort_t* Whh_f = (const ushort_t*)d_in[3];
  const ushort_t* b_f   = (const ushort_t*)d_in[4];
  const ushort_t* Wih_b = (const ushort_t*)d_in[5];
  const ushort_t* Whh_b = (const ushort_t*)d_in[6];
  const ushort_t* b_b   = (const ushort_t*)d_in[7];
  const ushort_t* W1    = (const ushort_t*)d_in[8];
  const ushort_t* W2    = (const ushort_t*)d_in[9];
  const ushort_t* W3    = (const ushort_t*)d_in[10];
  const ushort_t* b3    = (const ushort_t*)d_in[11];
  ushort_t* out = (ushort_t*)d_out;
  char* ws = (char*)d_ws;

  const bool conc = ws_size >= (size_t)NEED_CONC;
  ushort_t* hist = (ushort_t*)(ws + OFF_XZ + (conc ? 33554432u : 16777216u));

  hipMemsetAsync(ws, 0, 4096, stream);               // dtype flag area
  detect_k<<<dim3(1), dim3(256), 0, stream>>>((const uint32_t*)d_in[0], ws);

  dim3 blk(256);
  if (conc){
    gemm_k<0><<<dim3(64,8,1), blk, 0, stream>>>(x, nullptr, Wih_f, b_f, nullptr, ws,
                                                DB_, DB_, DB_, 0, 1, 1, 0,0, 0L);
    gemm_k<0><<<dim3(64,8,1), blk, 0, stream>>>(x, nullptr, Wih_b, b_b, nullptr, ws,
                                                DB_, DB_, DB_, 1, 1, 1, 0,0, (long)XZ_DIR_ELEMS);
    rec_k<<<dim3(4), blk, 0, stream>>>(Whh_f, Whh_b, ws, hist, 0, (long)XZ_DIR_ELEMS, 1);
  } else {
    gemm_k<0><<<dim3(64,8,1), blk, 0, stream>>>(x, nullptr, Wih_f, b_f, nullptr, ws,
                                                DB_, DB_, DB_, 0, 1, 1, 0,0, 0L);
    rec_k<<<dim3(2), blk, 0, stream>>>(Whh_f, Whh_b, ws, hist, 0, 0L, 0);
    gemm_k<0><<<dim3(64,8,1), blk, 0, stream>>>(x, nullptr, Wih_b, b_b, nullptr, ws,
                                                DB_, DB_, DB_, 1, 1, 1, 0,0, 0L);
    rec_k<<<dim3(2), blk, 0, stream>>>(Whh_f, Whh_b, ws, hist, 1, 0L, 0);
  }
  // attention
  c1_k<<<dim3(2048), blk, 0, stream>>>(ws, W1, hist);
  c2_k<<<dim3(2048), blk, 0, stream>>>(ws, W2, mask);
  // context = watt @ h (per batch), B row-major from hist
  gemm_k<3><<<dim3(2,4,32), blk, 0, stream>>>((ushort_t*)(ws+OFF_WATT), nullptr,
                                              hist, nullptr,
                                              (ushort_t*)(ws+OFF_CTX), ws,
                                              256, 512, 256, 0, 0, 0,
                                              65536L, 131072L, 131072L);
  // y = concat(h, ctx) @ W3^T + b3 -> d_out (dtype-matched store)
  gemm_k<2><<<dim3(64,4,1), blk, 0, stream>>>(hist, (ushort_t*)(ws+OFF_CTX),
                                              W3, b3, out, ws,
                                              512, 1024, 1024, 0, 0, 1, 0,0, 0L);
}

// Round 7
// 4221.672 us; speedup vs baseline: 1.2350x; 1.2350x over previous
//
#include <hip/hip_runtime.h>
#include <stdint.h>

// ---------------- problem constants ----------------
#define B_   32
#define T_   256
#define H_   256      // per-direction hidden
#define DB_  768      // input dim
#define DL_  512      // 2*H

// ---------------- workspace layout (bytes) ----------------
#define OFF_DTYPE 0u                          // int: 1 = inputs bf16, 0 = f32
#define OFF_XZ    69632u                      // swizzled xz, per-dir stride 8M elems (16 MB)
#define XZ_DIR_ELEMS 8388608u
#define NEED_CONC (OFF_XZ + 2u*16777216u + 8388608u)
// ---- aliased into the xz region (xz dead after rec) ----
#define OFF_CTX   OFF_XZ                      // context [32][256][512] bf16 = 8 MB
#define OFF_WATT  (OFF_XZ + 8388608u)         // attn weights [32][256][256] bf16 = 4 MB
#define OFF_SQ    (OFF_XZ + 12582912u)        // [8192][10] f32
#define OFF_SK    (OFF_SQ + 327680u)          // [8192][10] f32

typedef __attribute__((ext_vector_type(8))) short bf16x8;
typedef __attribute__((ext_vector_type(4))) float f32x4;
typedef unsigned short ushort_t;

__device__ __forceinline__ float b2f(ushort_t u){ union{float f; uint32_t i;} v; v.i=((uint32_t)u)<<16; return v.f; }
__device__ __forceinline__ ushort_t f2b(float f){
  union{float ff; uint32_t i;} v; v.ff=f;
  uint32_t r = v.i + 0x7fffu + ((v.i>>16)&1u);
  return (ushort_t)(r>>16);
}
__device__ __forceinline__ float sig_f(float x){ return 1.f/(1.f+__expf(-x)); }
__device__ __forceinline__ float tanh_f(float x){ return 1.f - 2.f/(1.f+__expf(2.f*x)); }

__device__ __forceinline__ bf16x8 load8(const ushort_t* p, size_t idx, int isbf){
  if (isbf) return *(const bf16x8*)(p + idx);
  const float* f = (const float*)p;
  bf16x8 r;
  #pragma unroll
  for (int i=0;i<8;++i) r[i] = (short)f2b(f[idx+i]);
  return r;
}
// vectorized variant (f32 path uses 2x b128 loads instead of 8 scalars)
__device__ __forceinline__ bf16x8 load8v(const ushort_t* p, size_t idx, int isbf){
  if (isbf) return *(const bf16x8*)(p + idx);
  const float* f = (const float*)p + idx;
  f32x4 a = *(const f32x4*)f;
  f32x4 b = *(const f32x4*)(f + 4);
  bf16x8 r;
  #pragma unroll
  for (int i=0;i<4;++i){ r[i] = (short)f2b(a[i]); r[4+i] = (short)f2b(b[i]); }
  return r;
}
__device__ __forceinline__ float loadS(const ushort_t* p, size_t idx, int isbf){
  return isbf ? b2f(p[idx]) : ((const float*)p)[idx];
}

// =====================================================================
// dtype probe (R3-verified): votes f32 vs bf16 from exponent stats.
// =====================================================================
__global__ void detect_k(const uint32_t* __restrict__ x, char* __restrict__ ws){
  __shared__ int cnt;
  if (threadIdx.x == 0) cnt = 0;
  __syncthreads();
  int local = 0;
  #pragma unroll
  for (int i=0;i<4;++i){
    uint32_t w = x[threadIdx.x*4 + i];
    uint32_t lo = w & 0xFFFFu;
    int e = (int)((lo >> 7) & 0xFFu);
    if (e >= 118 && e <= 130) local++;
  }
  atomicAdd(&cnt, local);
  __syncthreads();
  if (threadIdx.x == 0) *(int*)(ws + OFF_DTYPE) = (cnt > 512) ? 1 : 0;
}

// =====================================================================
// Generic 128x128-tile bf16 MFMA GEMM (unchanged, R4-R8-verified).
// =====================================================================
template<int MODE>
__global__ __launch_bounds__(256,2) void gemm_k(
    const ushort_t* __restrict__ A0, const ushort_t* __restrict__ A2,
    const ushort_t* __restrict__ Bm, const ushort_t* __restrict__ bias,
    ushort_t* __restrict__ Cout, char* __restrict__ ws,
    int lda, int ldb, int K, int dir, int aIn, int bIn,
    long aOffZ, long bOffZ, long cOffZ)
{
  __shared__ ushort_t As[8192];
  __shared__ ushort_t Bs[8192];
  const int dtf = *(const int*)(ws + OFF_DTYPE);
  const int aBF = aIn ? dtf : 1;
  const int bBF = bIn ? dtf : 1;
  const int tid = threadIdx.x;
  const int l  = tid & 63, wv = tid >> 6;
  const int lc = l & 15,  lh = l >> 4;
  const int m0 = blockIdx.x * 128, n0 = blockIdx.y * 128;
  const int z  = blockIdx.z;
  const ushort_t* Abase = A0 + (size_t)z * aOffZ;
  const ushort_t* Bbase = Bm + (size_t)z * bOffZ;
  const int srow = tid >> 3;
  const int sch  = tid & 7;

  f32x4 acc[4][4];
  #pragma unroll
  for (int i=0;i<4;++i)
    #pragma unroll
    for (int j=0;j<4;++j) acc[i][j] = (f32x4){0.f,0.f,0.f,0.f};

  bf16x8 ra[4], rb[4];
  #pragma unroll
  for (int p=0;p<4;++p){
    int row = p*32 + srow;
    int kk  = (sch ^ (row & 7)) * 8;
    ra[p] = load8(Abase, (size_t)(m0+row)*lda + kk, aBF);
    if (MODE==3){
      int q = p*256 + tid, kr = q>>4, c = q&15;
      rb[p] = load8(Bbase, (size_t)kr*ldb + n0 + c*8, 1);
    } else {
      rb[p] = load8(Bbase, (size_t)(n0+row)*ldb + kk, bBF);
    }
  }

  const int mo = (wv&1)*64, no = (wv>>1)*64;

  for (int k0 = 0; k0 < K; k0 += 64) {
    #pragma unroll
    for (int p=0;p<4;++p){
      int row = p*32 + srow;
      *(bf16x8*)(&As[row*64 + sch*8]) = ra[p];
      if (MODE==3){
        int q = p*256 + tid, kr = q>>4, c = q&15;
        *(bf16x8*)(&Bs[kr*128 + c*8]) = rb[p];
      } else {
        *(bf16x8*)(&Bs[row*64 + sch*8]) = rb[p];
      }
    }
    __syncthreads();
    int k1 = k0 + 64;
    if (k1 < K) {
      #pragma unroll
      for (int p=0;p<4;++p){
        int row = p*32 + srow;
        int kk  = k1 + (sch ^ (row & 7)) * 8;
        if (MODE==2 && k1 >= 512)
          ra[p] = load8(A2, (size_t)(m0+row)*512 + (kk - 512), 1);
        else
          ra[p] = load8(Abase, (size_t)(m0+row)*lda + kk, aBF);
        if (MODE==3){
          int q = p*256 + tid, kr = q>>4, c = q&15;
          rb[p] = load8(Bbase, (size_t)(k1+kr)*ldb + n0 + c*8, 1);
        } else {
          rb[p] = load8(Bbase, (size_t)(n0+row)*ldb + kk, bBF);
        }
      }
    }
    #pragma unroll
    for (int kc=0;kc<2;++kc){
      bf16x8 af[4], bfv[4];
      #pragma unroll
      for (int it=0;it<4;++it){
        int m = mo + it*16 + lc;
        int gc = kc*4 + lh;
        af[it]  = *(const bf16x8*)(&As[m*64 + ((gc ^ (m&7))*8)]);
        int n = no + it*16 + lc;
        if (MODE==3){
          #pragma unroll
          for (int j=0;j<8;++j) bfv[it][j] = (short)Bs[(kc*32 + lh*8 + j)*128 + n];
        } else {
          bfv[it] = *(const bf16x8*)(&Bs[n*64 + ((gc ^ (n&7))*8)]);
        }
      }
      #pragma unroll
      for (int mt=0;mt<4;++mt)
        #pragma unroll
        for (int nt=0;nt<4;++nt)
          acc[mt][nt] = __builtin_amdgcn_mfma_f32_16x16x32_bf16(af[mt], bfv[nt], acc[mt][nt], 0,0,0);
    }
    __syncthreads();
  }

  ushort_t* xzsw = (ushort_t*)(ws + OFF_XZ);
  #pragma unroll
  for (int mt=0;mt<4;++mt){
    #pragma unroll
    for (int nt=0;nt<4;++nt){
      #pragma unroll
      for (int r=0;r<4;++r){
        int m = m0 + mo + mt*16 + lh*4 + r;
        int n = n0 + no + nt*16 + lc;
        float v = acc[mt][nt][r];
        if (MODE==0){
          v += loadS(bias, n, bBF);
          int b = m >> 8, t = m & 255;
          int ts = dir ? (255 - t) : t;
          int q = n >> 8, jm = n & 255;
          int w = jm >> 6, jj = jm & 63, wvv = jj >> 4, colj = jj & 15;
          int lane = ((b >> 2) & 3)*16 + colj;
          int idx  = (b >> 4)*16 + q*4 + (b & 3);
          size_t e = (((size_t)(w*4 + wvv)*256 + ts)*2048) + (size_t)lane*32 + idx;
          xzsw[e + (size_t)cOffZ] = f2b(v);
        } else if (MODE==3){
          Cout[(size_t)z*cOffZ + (size_t)m*DL_ + n] = f2b(v);
        } else {
          v += loadS(bias, n, bBF);
          if (dtf) Cout[(size_t)m*DL_ + n] = f2b(v);
          else     ((float*)Cout)[(size_t)m*DL_ + n] = v;
        }
      }
    }
  }
}

// =====================================================================
// BiLSTM recurrence, v13 — in-block, budget-fixed (R6 post-mortem).
//   Cross-block floor is 256*L ≈ 850us (R0/R5 both fit 256*T law) ->
//   in-block is the only escape. R6's failures fixed:
//   (1) VGPR wall: 8 waves x 64 (512 thr). Whh 8 K-slices split:
//       kc4..7 VGPR-resident (32 frags = 128 regs/lane), kc2..3 LDS
//       (128KB), kc0..1 streamed from L2 per step (single 8-frag
//       buffer, 32 regs). Total ~245 addressable regs — under 256.
//   (2) h bank conflicts: XOR-swizzle byte^=((row&7)<<4) on BOTH write
//       and read (permutes whole 16B blocks -> b128 A-frags intact);
//       h double-buffered (2x8KB) -> ONE barrier/step.
//   Each block: one (dir x batch-half), 16 batches x 256 units; wave w
//   owns units [32w,32w+32) x all 4 gates (cell is wave-local). All
//   frag layouts / xz swizzle / hist layout / cell math are the
//   R0-proven conventions. No inter-block traffic at all.
// =====================================================================
__global__ __launch_bounds__(512,1) void rec_k(
    const ushort_t* __restrict__ Whh_f, const ushort_t* __restrict__ Whh_b,
    char* __restrict__ ws, ushort_t* __restrict__ hist,
    int dParam, long xzDirStride, int concMode)
{
  __shared__ ushort_t sm[73728];   // 128KB weights + 2x8KB h dbuf = 144KB
  const int bid = (int)blockIdx.x;
  const int d   = concMode ? (bid >> 1) : dParam;
  const int BH  = bid & 1;         // batch half
  const int tid = threadIdx.x;
  const int w = tid >> 6, l = tid & 63;
  const int lc = l & 15, lh = l >> 4;
  const int dtf = *(const int*)(ws + OFF_DTYPE);

  const ushort_t* xz  = (const ushort_t*)(ws + OFF_XZ) + (size_t)d * xzDirStride;
  const ushort_t* Whh = d ? Whh_b : Whh_f;
  uint32_t* histw = (uint32_t*)hist;

  // ---- stage: kc4..7 -> VGPR frags, kc2..3 -> LDS ----
  bf16x8 wreg[32];
  #pragma unroll
  for (int kc=0;kc<4;++kc)
    #pragma unroll
    for (int gt=0;gt<4;++gt)
      #pragma unroll
      for (int uh=0;uh<2;++uh){
        int row = gt*256 + w*32 + uh*16 + lc;
        wreg[kc*8+gt*2+uh] = load8v(Whh, (size_t)row*256 + (size_t)(kc+4)*32 + lh*8, dtf);
      }
  #pragma unroll
  for (int kc=0;kc<2;++kc)
    #pragma unroll
    for (int gt=0;gt<4;++gt)
      #pragma unroll
      for (int uh=0;uh<2;++uh){
        int row = gt*256 + w*32 + uh*16 + lc;
        bf16x8 v = load8v(Whh, (size_t)row*256 + (size_t)(kc+2)*32 + lh*8, dtf);
        *(bf16x8*)(&sm[(size_t)(w*16 + kc*8+gt*2+uh)*512 + (size_t)l*8]) = v;
      }
  __syncthreads();

  float cst[8];
  #pragma unroll
  for (int i=0;i<8;++i) cst[i] = 0.f;

  for (int t=0; t<T_; ++t){
    const int ts = d ? (255 - t) : t;
    char* hsw = (char*)&sm[65536 + (t & 1)*4096];          // h(t) write buf
    const char* hsr = (const char*)&sm[65536 + ((t ^ 1) & 1)*4096]; // h(t-1)

    // xz prefetch: this wave's 2 unit-groups g = w*2+uh (R0 swizzle layout)
    bf16x8 xzv[2][2];
    #pragma unroll
    for (int uh=0;uh<2;++uh){
      size_t e = ((size_t)(w*2+uh)*256 + (size_t)t)*2048 + (size_t)l*32 + (size_t)BH*16;
      xzv[uh][0] = *(const bf16x8*)(xz + e);
      xzv[uh][1] = *(const bf16x8*)(xz + e + 8);
    }

    f32x4 acc[8];
    #pragma unroll
    for (int i=0;i<8;++i) acc[i] = (f32x4){0.f,0.f,0.f,0.f};

    if (t > 0){
      // stream kc0 (issued early; consumed after resident MFMAs)
      bf16x8 sreg[8];
      #pragma unroll
      for (int gt=0;gt<4;++gt)
        #pragma unroll
        for (int uh=0;uh<2;++uh)
          sreg[gt*2+uh] = load8v(Whh, (size_t)(gt*256 + w*32 + uh*16 + lc)*256 + lh*8, dtf);

      // kc4..7 from VGPR-resident frags
      #pragma unroll
      for (int kc=0;kc<4;++kc){
        bf16x8 a = *(const bf16x8*)(hsr + lc*512 + ((((kc+4)*64 + lh*16)) ^ ((lc&7)<<4)));
        #pragma unroll
        for (int ti=0;ti<8;++ti)
          acc[ti] = __builtin_amdgcn_mfma_f32_16x16x32_bf16(a, wreg[kc*8+ti], acc[ti], 0,0,0);
      }
      // kc2..3 from LDS
      #pragma unroll
      for (int kc=0;kc<2;++kc){
        bf16x8 a = *(const bf16x8*)(hsr + lc*512 + ((((kc+2)*64 + lh*16)) ^ ((lc&7)<<4)));
        #pragma unroll
        for (int ti=0;ti<8;++ti){
          bf16x8 bfr = *(const bf16x8*)(&sm[(size_t)(w*16 + kc*8+ti)*512 + (size_t)l*8]);
          acc[ti] = __builtin_amdgcn_mfma_f32_16x16x32_bf16(a, bfr, acc[ti], 0,0,0);
        }
      }
      // kc0 (streamed, now arrived)
      {
        bf16x8 a = *(const bf16x8*)(hsr + lc*512 + (((0*64 + lh*16)) ^ ((lc&7)<<4)));
        #pragma unroll
        for (int ti=0;ti<8;++ti)
          acc[ti] = __builtin_amdgcn_mfma_f32_16x16x32_bf16(a, sreg[ti], acc[ti], 0,0,0);
      }
      // kc1: reissue into the same buffer, consume
      #pragma unroll
      for (int gt=0;gt<4;++gt)
        #pragma unroll
        for (int uh=0;uh<2;++uh)
          sreg[gt*2+uh] = load8v(Whh, (size_t)(gt*256 + w*32 + uh*16 + lc)*256 + 32 + lh*8, dtf);
      {
        bf16x8 a = *(const bf16x8*)(hsr + lc*512 + (((1*64 + lh*16)) ^ ((lc&7)<<4)));
        #pragma unroll
        for (int ti=0;ti<8;++ti)
          acc[ti] = __builtin_amdgcn_mfma_f32_16x16x32_bf16(a, sreg[ti], acc[ti], 0,0,0);
      }
    }

    // ---- cell + stores (writes go to the OTHER h buffer; no pre-barrier) ----
    #pragma unroll
    for (int uh=0;uh<2;++uh){
      #pragma unroll
      for (int r=0;r<4;++r){
        float zi = acc[0*2+uh][r] + b2f((ushort_t)xzv[uh][(r+0 )>>3][(r+0 )&7]);
        float zf = acc[1*2+uh][r] + b2f((ushort_t)xzv[uh][(r+4 )>>3][(r+4 )&7]);
        float zg = acc[2*2+uh][r] + b2f((ushort_t)xzv[uh][(r+8 )>>3][(r+8 )&7]);
        float zo = acc[3*2+uh][r] + b2f((ushort_t)xzv[uh][(r+12)>>3][(r+12)&7]);
        float ig = sig_f(zi), fg = sig_f(zf), gg = tanh_f(zg), og = sig_f(zo);
        float c = fg * cst[uh*4+r] + ig * gg;
        cst[uh*4+r] = c;
        float h = og * tanh_f(c);
        ushort_t h16 = f2b(h);
        uint32_t mine = (uint32_t)h16;
        uint32_t partner = (uint32_t)__shfl_xor((int)mine, 1);
        if ((lc & 1) == 0){
          uint32_t packed = mine | (partner << 16);
          int lb = lh*4 + r;               // local batch 0..15
          int u  = w*32 + uh*16 + lc;      // even unit
          *(uint32_t*)(hsw + lb*512 + ((u*2) ^ ((lb&7)<<4))) = packed;
          histw[(((size_t)((BH*16 + lb)*256 + ts))*512 + (size_t)(d*256 + u)) >> 1] = packed;
        }
      }
    }
    __syncthreads();   // h(t) visible before step t+1 reads it
  }
}

// =====================================================================
// C1: sq[m][x] = h[m]·W1[x][0:512], sk[m][x] = h[m]·W1[x][512:1024]
// =====================================================================
__global__ __launch_bounds__(256) void c1_k(char* __restrict__ ws, const ushort_t* __restrict__ W1,
                                            const ushort_t* __restrict__ hist)
{
  float* sq = (float*)(ws + OFF_SQ);
  float* sk = (float*)(ws + OFF_SK);
  const int dtf = *(const int*)(ws + OFF_DTYPE);
  int tid = threadIdx.x; int wv = tid>>6, l = tid&63;
  int row = blockIdx.x*4 + wv;
  bf16x8 hv = *(const bf16x8*)(hist + (size_t)row*512 + l*8);
  float hf[8];
  #pragma unroll
  for (int i=0;i<8;++i) hf[i] = b2f((ushort_t)hv[i]);
  #pragma unroll
  for (int x=0;x<10;++x){
    bf16x8 qv = load8(W1, (size_t)x*1024 + l*8, dtf);
    bf16x8 kv = load8(W1, (size_t)x*1024 + 512 + l*8, dtf);
    float pq=0.f, pk=0.f;
    #pragma unroll
    for (int i=0;i<8;++i){ pq += hf[i]*b2f((ushort_t)qv[i]); pk += hf[i]*b2f((ushort_t)kv[i]); }
    #pragma unroll
    for (int off=32; off>0; off>>=1){ pq += __shfl_xor(pq, off, 64); pk += __shfl_xor(pk, off, 64); }
    if (l == 0){ sq[row*10 + x] = pq; sk[row*10 + x] = pk; }
  }
}

// =====================================================================
// C2: a = sum_x tanh(sq+sk)*W2[x]; masked softmax -> bf16 watt
// =====================================================================
__global__ __launch_bounds__(256) void c2_k(char* __restrict__ ws, const ushort_t* __restrict__ W2,
                                            const ushort_t* __restrict__ mask)
{
  const float* sq = (const float*)(ws + OFF_SQ);
  const float* sk = (const float*)(ws + OFF_SK);
  ushort_t* watt = (ushort_t*)(ws + OFF_WATT);
  const int dtf = *(const int*)(ws + OFF_DTYPE);
  int tid = threadIdx.x; int wv = tid>>6, l = tid&63;
  int bq = blockIdx.x*4 + wv;
  int b  = bq >> 8;
  float sqv[10], w2v[10];
  #pragma unroll
  for (int x=0;x<10;++x){ sqv[x] = sq[(size_t)bq*10+x]; w2v[x] = loadS(W2, x, dtf); }
  float a[4];
  #pragma unroll
  for (int kk=0;kk<4;++kk){
    int k = kk*64 + l;
    const float* skp = sk + ((size_t)b*256 + k)*10;
    float s = 0.f;
    #pragma unroll
    for (int x=0;x<10;++x) s += tanh_f(sqv[x] + skp[x]) * w2v[x];
    float mval = loadS(mask, (size_t)b*256 + k, dtf);
    a[kk] = (mval == 0.f) ? -1e30f : s;
  }
  float mx = fmaxf(fmaxf(a[0],a[1]), fmaxf(a[2],a[3]));
  #pragma unroll
  for (int off=32; off>0; off>>=1) mx = fmaxf(mx, __shfl_xor(mx, off, 64));
  float e[4], ssum=0.f;
  #pragma unroll
  for (int kk=0;kk<4;++kk){ e[kk] = __expf(a[kk]-mx); ssum += e[kk]; }
  #pragma unroll
  for (int off=32; off>0; off>>=1) ssum += __shfl_xor(ssum, off, 64);
  float inv = 1.f/ssum;
  #pragma unroll
  for (int kk=0;kk<4;++kk) watt[(size_t)bq*256 + kk*64 + l] = f2b(e[kk]*inv);
}

// =====================================================================
extern "C" void kernel_launch(void* const* d_in, const int* in_sizes, int n_in,
                              void* d_out, int out_size, void* d_ws, size_t ws_size,
                              hipStream_t stream)
{
  const ushort_t* x     = (const ushort_t*)d_in[0];
  const ushort_t* mask  = (const ushort_t*)d_in[1];
  const ushort_t* Wih_f = (const ushort_t*)d_in[2];
  const ushort_t* Whh_f = (const ushort_t*)d_in[3];
  const ushort_t* b_f   = (const ushort_t*)d_in[4];
  const ushort_t* Wih_b = (const ushort_t*)d_in[5];
  const ushort_t* Whh_b = (const ushort_t*)d_in[6];
  const ushort_t* b_b   = (const ushort_t*)d_in[7];
  const ushort_t* W1    = (const ushort_t*)d_in[8];
  const ushort_t* W2    = (const ushort_t*)d_in[9];
  const ushort_t* W3    = (const ushort_t*)d_in[10];
  const ushort_t* b3    = (const ushort_t*)d_in[11];
  ushort_t* out = (ushort_t*)d_out;
  char* ws = (char*)d_ws;

  const bool conc = ws_size >= (size_t)NEED_CONC;
  ushort_t* hist = (ushort_t*)(ws + OFF_XZ + (conc ? 33554432u : 16777216u));

  hipMemsetAsync(ws, 0, 4096, stream);               // dtype flag area
  detect_k<<<dim3(1), dim3(256), 0, stream>>>((const uint32_t*)d_in[0], ws);

  dim3 blk(256);
  dim3 rblk(512);
  if (conc){
    gemm_k<0><<<dim3(64,8,1), blk, 0, stream>>>(x, nullptr, Wih_f, b_f, nullptr, ws,
                                                DB_, DB_, DB_, 0, 1, 1, 0,0, 0L);
    gemm_k<0><<<dim3(64,8,1), blk, 0, stream>>>(x, nullptr, Wih_b, b_b, nullptr, ws,
                                                DB_, DB_, DB_, 1, 1, 1, 0,0, (long)XZ_DIR_ELEMS);
    rec_k<<<dim3(4), rblk, 0, stream>>>(Whh_f, Whh_b, ws, hist, 0, (long)XZ_DIR_ELEMS, 1);
  } else {
    gemm_k<0><<<dim3(64,8,1), blk, 0, stream>>>(x, nullptr, Wih_f, b_f, nullptr, ws,
                                                DB_, DB_, DB_, 0, 1, 1, 0,0, 0L);
    rec_k<<<dim3(2), rblk, 0, stream>>>(Whh_f, Whh_b, ws, hist, 0, 0L, 0);
    gemm_k<0><<<dim3(64,8,1), blk, 0, stream>>>(x, nullptr, Wih_b, b_b, nullptr, ws,
                                                DB_, DB_, DB_, 1, 1, 1, 0,0, 0L);
    rec_k<<<dim3(2), rblk, 0, stream>>>(Whh_f, Whh_b, ws, hist, 1, 0L, 0);
  }
  // attention
  c1_k<<<dim3(2048), blk, 0, stream>>>(ws, W1, hist);
  c2_k<<<dim3(2048), blk, 0, stream>>>(ws, W2, mask);
  // context = watt @ h (per batch), B row-major from hist
  gemm_k<3><<<dim3(2,4,32), blk, 0, stream>>>((ushort_t*)(ws+OFF_WATT), nullptr,
                                              hist, nullptr,
                                              (ushort_t*)(ws+OFF_CTX), ws,
                                              256, 512, 256, 0, 0, 0,
                                              65536L, 131072L, 131072L);
  // y = concat(h, ctx) @ W3^T + b3 -> d_out (dtype-matched store)
  gemm_k<2><<<dim3(64,4,1), blk, 0, stream>>>(hist, (ushort_t*)(ws+OFF_CTX),
                                              W3, b3, out, ws,
                                              512, 1024, 1024, 0, 0, 1, 0,0, 0L);
}

// Round 8
// 4220.539 us; speedup vs baseline: 1.2353x; 1.0003x over previous
//
#include <hip/hip_runtime.h>
#include <stdint.h>

// ---------------- problem constants ----------------
#define B_   32
#define T_   256
#define H_   256      // per-direction hidden
#define DB_  768      // input dim
#define DL_  512      // 2*H

// ---------------- workspace layout (bytes) ----------------
#define OFF_DTYPE 0u                          // int: 1 = inputs bf16, 0 = f32
#define OFF_XZ    69632u                      // swizzled xz, per-dir stride 8M elems (16 MB)
#define XZ_DIR_ELEMS 8388608u
#define NEED_CONC (OFF_XZ + 2u*16777216u + 8388608u)
// ---- aliased into the xz region (xz dead after rec) ----
#define OFF_CTX   OFF_XZ                      // context [32][256][512] bf16 = 8 MB
#define OFF_WATT  (OFF_XZ + 8388608u)         // attn weights [32][256][256] bf16 = 4 MB
#define OFF_SQ    (OFF_XZ + 12582912u)        // [8192][10] f32
#define OFF_SK    (OFF_SQ + 327680u)          // [8192][10] f32

typedef __attribute__((ext_vector_type(8))) short bf16x8;
typedef __attribute__((ext_vector_type(4))) float f32x4;
typedef unsigned short ushort_t;

__device__ __forceinline__ float b2f(ushort_t u){ union{float f; uint32_t i;} v; v.i=((uint32_t)u)<<16; return v.f; }
__device__ __forceinline__ ushort_t f2b(float f){
  union{float ff; uint32_t i;} v; v.ff=f;
  uint32_t r = v.i + 0x7fffu + ((v.i>>16)&1u);
  return (ushort_t)(r>>16);
}
__device__ __forceinline__ float sig_f(float x){ return 1.f/(1.f+__expf(-x)); }
__device__ __forceinline__ float tanh_f(float x){ return 1.f - 2.f/(1.f+__expf(2.f*x)); }

__device__ __forceinline__ bf16x8 load8(const ushort_t* p, size_t idx, int isbf){
  if (isbf) return *(const bf16x8*)(p + idx);
  const float* f = (const float*)p;
  bf16x8 r;
  #pragma unroll
  for (int i=0;i<8;++i) r[i] = (short)f2b(f[idx+i]);
  return r;
}
// vectorized variant (f32 path uses 2x b128 loads instead of 8 scalars)
__device__ __forceinline__ bf16x8 load8v(const ushort_t* p, size_t idx, int isbf){
  if (isbf) return *(const bf16x8*)(p + idx);
  const float* f = (const float*)p + idx;
  f32x4 a = *(const f32x4*)f;
  f32x4 b = *(const f32x4*)(f + 4);
  bf16x8 r;
  #pragma unroll
  for (int i=0;i<4;++i){ r[i] = (short)f2b(a[i]); r[4+i] = (short)f2b(b[i]); }
  return r;
}
__device__ __forceinline__ float loadS(const ushort_t* p, size_t idx, int isbf){
  return isbf ? b2f(p[idx]) : ((const float*)p)[idx];
}

// =====================================================================
// dtype probe (R3-verified): votes f32 vs bf16 from exponent stats.
// =====================================================================
__global__ void detect_k(const uint32_t* __restrict__ x, char* __restrict__ ws){
  __shared__ int cnt;
  if (threadIdx.x == 0) cnt = 0;
  __syncthreads();
  int local = 0;
  #pragma unroll
  for (int i=0;i<4;++i){
    uint32_t w = x[threadIdx.x*4 + i];
    uint32_t lo = w & 0xFFFFu;
    int e = (int)((lo >> 7) & 0xFFu);
    if (e >= 118 && e <= 130) local++;
  }
  atomicAdd(&cnt, local);
  __syncthreads();
  if (threadIdx.x == 0) *(int*)(ws + OFF_DTYPE) = (cnt > 512) ? 1 : 0;
}

// =====================================================================
// Generic 128x128-tile bf16 MFMA GEMM (unchanged, R4-R8-verified).
// =====================================================================
template<int MODE>
__global__ __launch_bounds__(256,2) void gemm_k(
    const ushort_t* __restrict__ A0, const ushort_t* __restrict__ A2,
    const ushort_t* __restrict__ Bm, const ushort_t* __restrict__ bias,
    ushort_t* __restrict__ Cout, char* __restrict__ ws,
    int lda, int ldb, int K, int dir, int aIn, int bIn,
    long aOffZ, long bOffZ, long cOffZ)
{
  __shared__ ushort_t As[8192];
  __shared__ ushort_t Bs[8192];
  const int dtf = *(const int*)(ws + OFF_DTYPE);
  const int aBF = aIn ? dtf : 1;
  const int bBF = bIn ? dtf : 1;
  const int tid = threadIdx.x;
  const int l  = tid & 63, wv = tid >> 6;
  const int lc = l & 15,  lh = l >> 4;
  const int m0 = blockIdx.x * 128, n0 = blockIdx.y * 128;
  const int z  = blockIdx.z;
  const ushort_t* Abase = A0 + (size_t)z * aOffZ;
  const ushort_t* Bbase = Bm + (size_t)z * bOffZ;
  const int srow = tid >> 3;
  const int sch  = tid & 7;

  f32x4 acc[4][4];
  #pragma unroll
  for (int i=0;i<4;++i)
    #pragma unroll
    for (int j=0;j<4;++j) acc[i][j] = (f32x4){0.f,0.f,0.f,0.f};

  bf16x8 ra[4], rb[4];
  #pragma unroll
  for (int p=0;p<4;++p){
    int row = p*32 + srow;
    int kk  = (sch ^ (row & 7)) * 8;
    ra[p] = load8(Abase, (size_t)(m0+row)*lda + kk, aBF);
    if (MODE==3){
      int q = p*256 + tid, kr = q>>4, c = q&15;
      rb[p] = load8(Bbase, (size_t)kr*ldb + n0 + c*8, 1);
    } else {
      rb[p] = load8(Bbase, (size_t)(n0+row)*ldb + kk, bBF);
    }
  }

  const int mo = (wv&1)*64, no = (wv>>1)*64;

  for (int k0 = 0; k0 < K; k0 += 64) {
    #pragma unroll
    for (int p=0;p<4;++p){
      int row = p*32 + srow;
      *(bf16x8*)(&As[row*64 + sch*8]) = ra[p];
      if (MODE==3){
        int q = p*256 + tid, kr = q>>4, c = q&15;
        *(bf16x8*)(&Bs[kr*128 + c*8]) = rb[p];
      } else {
        *(bf16x8*)(&Bs[row*64 + sch*8]) = rb[p];
      }
    }
    __syncthreads();
    int k1 = k0 + 64;
    if (k1 < K) {
      #pragma unroll
      for (int p=0;p<4;++p){
        int row = p*32 + srow;
        int kk  = k1 + (sch ^ (row & 7)) * 8;
        if (MODE==2 && k1 >= 512)
          ra[p] = load8(A2, (size_t)(m0+row)*512 + (kk - 512), 1);
        else
          ra[p] = load8(Abase, (size_t)(m0+row)*lda + kk, aBF);
        if (MODE==3){
          int q = p*256 + tid, kr = q>>4, c = q&15;
          rb[p] = load8(Bbase, (size_t)(k1+kr)*ldb + n0 + c*8, 1);
        } else {
          rb[p] = load8(Bbase, (size_t)(n0+row)*ldb + kk, bBF);
        }
      }
    }
    #pragma unroll
    for (int kc=0;kc<2;++kc){
      bf16x8 af[4], bfv[4];
      #pragma unroll
      for (int it=0;it<4;++it){
        int m = mo + it*16 + lc;
        int gc = kc*4 + lh;
        af[it]  = *(const bf16x8*)(&As[m*64 + ((gc ^ (m&7))*8)]);
        int n = no + it*16 + lc;
        if (MODE==3){
          #pragma unroll
          for (int j=0;j<8;++j) bfv[it][j] = (short)Bs[(kc*32 + lh*8 + j)*128 + n];
        } else {
          bfv[it] = *(const bf16x8*)(&Bs[n*64 + ((gc ^ (n&7))*8)]);
        }
      }
      #pragma unroll
      for (int mt=0;mt<4;++mt)
        #pragma unroll
        for (int nt=0;nt<4;++nt)
          acc[mt][nt] = __builtin_amdgcn_mfma_f32_16x16x32_bf16(af[mt], bfv[nt], acc[mt][nt], 0,0,0);
    }
    __syncthreads();
  }

  ushort_t* xzsw = (ushort_t*)(ws + OFF_XZ);
  #pragma unroll
  for (int mt=0;mt<4;++mt){
    #pragma unroll
    for (int nt=0;nt<4;++nt){
      #pragma unroll
      for (int r=0;r<4;++r){
        int m = m0 + mo + mt*16 + lh*4 + r;
        int n = n0 + no + nt*16 + lc;
        float v = acc[mt][nt][r];
        if (MODE==0){
          v += loadS(bias, n, bBF);
          int b = m >> 8, t = m & 255;
          int ts = dir ? (255 - t) : t;
          int q = n >> 8, jm = n & 255;
          int w = jm >> 6, jj = jm & 63, wvv = jj >> 4, colj = jj & 15;
          int lane = ((b >> 2) & 3)*16 + colj;
          int idx  = (b >> 4)*16 + q*4 + (b & 3);
          size_t e = (((size_t)(w*4 + wvv)*256 + ts)*2048) + (size_t)lane*32 + idx;
          xzsw[e + (size_t)cOffZ] = f2b(v);
        } else if (MODE==3){
          Cout[(size_t)z*cOffZ + (size_t)m*DL_ + n] = f2b(v);
        } else {
          v += loadS(bias, n, bBF);
          if (dtf) Cout[(size_t)m*DL_ + n] = f2b(v);
          else     ((float*)Cout)[(size_t)m*DL_ + n] = v;
        }
      }
    }
  }
}

// =====================================================================
// BiLSTM recurrence, v14 — v13 + forced 2-waves/EU register budget.
//   R7 post-mortem: FETCH (35 MB, KB units!) showed no HBM scratch, but
//   VGPR_Count=128 < wreg demand (128 for weights alone) -> compiler
//   targeted 4 waves/EU occupancy and spilled the resident weights to
//   (L2-cached) scratch: 15us/step, VALUBusy 28%/CU of spill movs.
//   LDS (144KB) already limits us to 1 block/CU = 2 waves/EU, so the
//   high-occupancy register target is pure waste. Fix: explicit
//   amdgpu_waves_per_eu(2,2) -> 256-reg budget; demand ~240 (wreg 128 +
//   sreg 32 + acc 32 (AGPR-eligible) + xzv 16 + cst 8 + addr ~25) fits.
//   Everything else is byte-identical to the R7 correctness-proven
//   kernel (layouts, swizzles, cell math, barriers).
// =====================================================================
__global__ __launch_bounds__(512) __attribute__((amdgpu_waves_per_eu(2,2))) void rec_k(
    const ushort_t* __restrict__ Whh_f, const ushort_t* __restrict__ Whh_b,
    char* __restrict__ ws, ushort_t* __restrict__ hist,
    int dParam, long xzDirStride, int concMode)
{
  __shared__ ushort_t sm[73728];   // 128KB weights + 2x8KB h dbuf = 144KB
  const int bid = (int)blockIdx.x;
  const int d   = concMode ? (bid >> 1) : dParam;
  const int BH  = bid & 1;         // batch half
  const int tid = threadIdx.x;
  const int w = tid >> 6, l = tid & 63;
  const int lc = l & 15, lh = l >> 4;
  const int dtf = *(const int*)(ws + OFF_DTYPE);

  const ushort_t* xz  = (const ushort_t*)(ws + OFF_XZ) + (size_t)d * xzDirStride;
  const ushort_t* Whh = d ? Whh_b : Whh_f;
  uint32_t* histw = (uint32_t*)hist;

  // ---- stage: kc4..7 -> VGPR frags, kc2..3 -> LDS ----
  bf16x8 wreg[32];
  #pragma unroll
  for (int kc=0;kc<4;++kc)
    #pragma unroll
    for (int gt=0;gt<4;++gt)
      #pragma unroll
      for (int uh=0;uh<2;++uh){
        int row = gt*256 + w*32 + uh*16 + lc;
        wreg[kc*8+gt*2+uh] = load8v(Whh, (size_t)row*256 + (size_t)(kc+4)*32 + lh*8, dtf);
      }
  #pragma unroll
  for (int kc=0;kc<2;++kc)
    #pragma unroll
    for (int gt=0;gt<4;++gt)
      #pragma unroll
      for (int uh=0;uh<2;++uh){
        int row = gt*256 + w*32 + uh*16 + lc;
        bf16x8 v = load8v(Whh, (size_t)row*256 + (size_t)(kc+2)*32 + lh*8, dtf);
        *(bf16x8*)(&sm[(size_t)(w*16 + kc*8+gt*2+uh)*512 + (size_t)l*8]) = v;
      }
  __syncthreads();

  float cst[8];
  #pragma unroll
  for (int i=0;i<8;++i) cst[i] = 0.f;

  for (int t=0; t<T_; ++t){
    const int ts = d ? (255 - t) : t;
    char* hsw = (char*)&sm[65536 + (t & 1)*4096];          // h(t) write buf
    const char* hsr = (const char*)&sm[65536 + ((t ^ 1) & 1)*4096]; // h(t-1)

    // xz prefetch: this wave's 2 unit-groups g = w*2+uh (R0 swizzle layout)
    bf16x8 xzv[2][2];
    #pragma unroll
    for (int uh=0;uh<2;++uh){
      size_t e = ((size_t)(w*2+uh)*256 + (size_t)t)*2048 + (size_t)l*32 + (size_t)BH*16;
      xzv[uh][0] = *(const bf16x8*)(xz + e);
      xzv[uh][1] = *(const bf16x8*)(xz + e + 8);
    }

    f32x4 acc[8];
    #pragma unroll
    for (int i=0;i<8;++i) acc[i] = (f32x4){0.f,0.f,0.f,0.f};

    if (t > 0){
      // stream kc0 (issued early; consumed after resident MFMAs)
      bf16x8 sreg[8];
      #pragma unroll
      for (int gt=0;gt<4;++gt)
        #pragma unroll
        for (int uh=0;uh<2;++uh)
          sreg[gt*2+uh] = load8v(Whh, (size_t)(gt*256 + w*32 + uh*16 + lc)*256 + lh*8, dtf);

      // kc4..7 from VGPR-resident frags
      #pragma unroll
      for (int kc=0;kc<4;++kc){
        bf16x8 a = *(const bf16x8*)(hsr + lc*512 + ((((kc+4)*64 + lh*16)) ^ ((lc&7)<<4)));
        #pragma unroll
        for (int ti=0;ti<8;++ti)
          acc[ti] = __builtin_amdgcn_mfma_f32_16x16x32_bf16(a, wreg[kc*8+ti], acc[ti], 0,0,0);
      }
      // kc2..3 from LDS
      #pragma unroll
      for (int kc=0;kc<2;++kc){
        bf16x8 a = *(const bf16x8*)(hsr + lc*512 + ((((kc+2)*64 + lh*16)) ^ ((lc&7)<<4)));
        #pragma unroll
        for (int ti=0;ti<8;++ti){
          bf16x8 bfr = *(const bf16x8*)(&sm[(size_t)(w*16 + kc*8+ti)*512 + (size_t)l*8]);
          acc[ti] = __builtin_amdgcn_mfma_f32_16x16x32_bf16(a, bfr, acc[ti], 0,0,0);
        }
      }
      // kc0 (streamed, now arrived)
      {
        bf16x8 a = *(const bf16x8*)(hsr + lc*512 + (((0*64 + lh*16)) ^ ((lc&7)<<4)));
        #pragma unroll
        for (int ti=0;ti<8;++ti)
          acc[ti] = __builtin_amdgcn_mfma_f32_16x16x32_bf16(a, sreg[ti], acc[ti], 0,0,0);
      }
      // kc1: reissue into the same buffer, consume
      #pragma unroll
      for (int gt=0;gt<4;++gt)
        #pragma unroll
        for (int uh=0;uh<2;++uh)
          sreg[gt*2+uh] = load8v(Whh, (size_t)(gt*256 + w*32 + uh*16 + lc)*256 + 32 + lh*8, dtf);
      {
        bf16x8 a = *(const bf16x8*)(hsr + lc*512 + (((1*64 + lh*16)) ^ ((lc&7)<<4)));
        #pragma unroll
        for (int ti=0;ti<8;++ti)
          acc[ti] = __builtin_amdgcn_mfma_f32_16x16x32_bf16(a, sreg[ti], acc[ti], 0,0,0);
      }
    }

    // ---- cell + stores (writes go to the OTHER h buffer; no pre-barrier) ----
    #pragma unroll
    for (int uh=0;uh<2;++uh){
      #pragma unroll
      for (int r=0;r<4;++r){
        float zi = acc[0*2+uh][r] + b2f((ushort_t)xzv[uh][(r+0 )>>3][(r+0 )&7]);
        float zf = acc[1*2+uh][r] + b2f((ushort_t)xzv[uh][(r+4 )>>3][(r+4 )&7]);
        float zg = acc[2*2+uh][r] + b2f((ushort_t)xzv[uh][(r+8 )>>3][(r+8 )&7]);
        float zo = acc[3*2+uh][r] + b2f((ushort_t)xzv[uh][(r+12)>>3][(r+12)&7]);
        float ig = sig_f(zi), fg = sig_f(zf), gg = tanh_f(zg), og = sig_f(zo);
        float c = fg * cst[uh*4+r] + ig * gg;
        cst[uh*4+r] = c;
        float h = og * tanh_f(c);
        ushort_t h16 = f2b(h);
        uint32_t mine = (uint32_t)h16;
        uint32_t partner = (uint32_t)__shfl_xor((int)mine, 1);
        if ((lc & 1) == 0){
          uint32_t packed = mine | (partner << 16);
          int lb = lh*4 + r;               // local batch 0..15
          int u  = w*32 + uh*16 + lc;      // even unit
          *(uint32_t*)(hsw + lb*512 + ((u*2) ^ ((lb&7)<<4))) = packed;
          histw[(((size_t)((BH*16 + lb)*256 + ts))*512 + (size_t)(d*256 + u)) >> 1] = packed;
        }
      }
    }
    __syncthreads();   // h(t) visible before step t+1 reads it
  }
}

// =====================================================================
// C1: sq[m][x] = h[m]·W1[x][0:512], sk[m][x] = h[m]·W1[x][512:1024]
// =====================================================================
__global__ __launch_bounds__(256) void c1_k(char* __restrict__ ws, const ushort_t* __restrict__ W1,
                                            const ushort_t* __restrict__ hist)
{
  float* sq = (float*)(ws + OFF_SQ);
  float* sk = (float*)(ws + OFF_SK);
  const int dtf = *(const int*)(ws + OFF_DTYPE);
  int tid = threadIdx.x; int wv = tid>>6, l = tid&63;
  int row = blockIdx.x*4 + wv;
  bf16x8 hv = *(const bf16x8*)(hist + (size_t)row*512 + l*8);
  float hf[8];
  #pragma unroll
  for (int i=0;i<8;++i) hf[i] = b2f((ushort_t)hv[i]);
  #pragma unroll
  for (int x=0;x<10;++x){
    bf16x8 qv = load8(W1, (size_t)x*1024 + l*8, dtf);
    bf16x8 kv = load8(W1, (size_t)x*1024 + 512 + l*8, dtf);
    float pq=0.f, pk=0.f;
    #pragma unroll
    for (int i=0;i<8;++i){ pq += hf[i]*b2f((ushort_t)qv[i]); pk += hf[i]*b2f((ushort_t)kv[i]); }
    #pragma unroll
    for (int off=32; off>0; off>>=1){ pq += __shfl_xor(pq, off, 64); pk += __shfl_xor(pk, off, 64); }
    if (l == 0){ sq[row*10 + x] = pq; sk[row*10 + x] = pk; }
  }
}

// =====================================================================
// C2: a = sum_x tanh(sq+sk)*W2[x]; masked softmax -> bf16 watt
// =====================================================================
__global__ __launch_bounds__(256) void c2_k(char* __restrict__ ws, const ushort_t* __restrict__ W2,
                                            const ushort_t* __restrict__ mask)
{
  const float* sq = (const float*)(ws + OFF_SQ);
  const float* sk = (const float*)(ws + OFF_SK);
  ushort_t* watt = (ushort_t*)(ws + OFF_WATT);
  const int dtf = *(const int*)(ws + OFF_DTYPE);
  int tid = threadIdx.x; int wv = tid>>6, l = tid&63;
  int bq = blockIdx.x*4 + wv;
  int b  = bq >> 8;
  float sqv[10], w2v[10];
  #pragma unroll
  for (int x=0;x<10;++x){ sqv[x] = sq[(size_t)bq*10+x]; w2v[x] = loadS(W2, x, dtf); }
  float a[4];
  #pragma unroll
  for (int kk=0;kk<4;++kk){
    int k = kk*64 + l;
    const float* skp = sk + ((size_t)b*256 + k)*10;
    float s = 0.f;
    #pragma unroll
    for (int x=0;x<10;++x) s += tanh_f(sqv[x] + skp[x]) * w2v[x];
    float mval = loadS(mask, (size_t)b*256 + k, dtf);
    a[kk] = (mval == 0.f) ? -1e30f : s;
  }
  float mx = fmaxf(fmaxf(a[0],a[1]), fmaxf(a[2],a[3]));
  #pragma unroll
  for (int off=32; off>0; off>>=1) mx = fmaxf(mx, __shfl_xor(mx, off, 64));
  float e[4], ssum=0.f;
  #pragma unroll
  for (int kk=0;kk<4;++kk){ e[kk] = __expf(a[kk]-mx); ssum += e[kk]; }
  #pragma unroll
  for (int off=32; off>0; off>>=1) ssum += __shfl_xor(ssum, off, 64);
  float inv = 1.f/ssum;
  #pragma unroll
  for (int kk=0;kk<4;++kk) watt[(size_t)bq*256 + kk*64 + l] = f2b(e[kk]*inv);
}

// =====================================================================
extern "C" void kernel_launch(void* const* d_in, const int* in_sizes, int n_in,
                              void* d_out, int out_size, void* d_ws, size_t ws_size,
                              hipStream_t stream)
{
  const ushort_t* x     = (const ushort_t*)d_in[0];
  const ushort_t* mask  = (const ushort_t*)d_in[1];
  const ushort_t* Wih_f = (const ushort_t*)d_in[2];
  const ushort_t* Whh_f = (const ushort_t*)d_in[3];
  const ushort_t* b_f   = (const ushort_t*)d_in[4];
  const ushort_t* Wih_b = (const ushort_t*)d_in[5];
  const ushort_t* Whh_b = (const ushort_t*)d_in[6];
  const ushort_t* b_b   = (const ushort_t*)d_in[7];
  const ushort_t* W1    = (const ushort_t*)d_in[8];
  const ushort_t* W2    = (const ushort_t*)d_in[9];
  const ushort_t* W3    = (const ushort_t*)d_in[10];
  const ushort_t* b3    = (const ushort_t*)d_in[11];
  ushort_t* out = (ushort_t*)d_out;
  char* ws = (char*)d_ws;

  const bool conc = ws_size >= (size_t)NEED_CONC;
  ushort_t* hist = (ushort_t*)(ws + OFF_XZ + (conc ? 33554432u : 16777216u));

  hipMemsetAsync(ws, 0, 4096, stream);               // dtype flag area
  detect_k<<<dim3(1), dim3(256), 0, stream>>>((const uint32_t*)d_in[0], ws);

  dim3 blk(256);
  dim3 rblk(512);
  if (conc){
    gemm_k<0><<<dim3(64,8,1), blk, 0, stream>>>(x, nullptr, Wih_f, b_f, nullptr, ws,
                                                DB_, DB_, DB_, 0, 1, 1, 0,0, 0L);
    gemm_k<0><<<dim3(64,8,1), blk, 0, stream>>>(x, nullptr, Wih_b, b_b, nullptr, ws,
                                                DB_, DB_, DB_, 1, 1, 1, 0,0, (long)XZ_DIR_ELEMS);
    rec_k<<<dim3(4), rblk, 0, stream>>>(Whh_f, Whh_b, ws, hist, 0, (long)XZ_DIR_ELEMS, 1);
  } else {
    gemm_k<0><<<dim3(64,8,1), blk, 0, stream>>>(x, nullptr, Wih_f, b_f, nullptr, ws,
                                                DB_, DB_, DB_, 0, 1, 1, 0,0, 0L);
    rec_k<<<dim3(2), rblk, 0, stream>>>(Whh_f, Whh_b, ws, hist, 0, 0L, 0);
    gemm_k<0><<<dim3(64,8,1), blk, 0, stream>>>(x, nullptr, Wih_b, b_b, nullptr, ws,
                                                DB_, DB_, DB_, 1, 1, 1, 0,0, 0L);
    rec_k<<<dim3(2), rblk, 0, stream>>>(Whh_f, Whh_b, ws, hist, 1, 0L, 0);
  }
  // attention
  c1_k<<<dim3(2048), blk, 0, stream>>>(ws, W1, hist);
  c2_k<<<dim3(2048), blk, 0, stream>>>(ws, W2, mask);
  // context = watt @ h (per batch), B row-major from hist
  gemm_k<3><<<dim3(2,4,32), blk, 0, stream>>>((ushort_t*)(ws+OFF_WATT), nullptr,
                                              hist, nullptr,
                                              (ushort_t*)(ws+OFF_CTX), ws,
                                              256, 512, 256, 0, 0, 0,
                                              65536L, 131072L, 131072L);
  // y = concat(h, ctx) @ W3^T + b3 -> d_out (dtype-matched store)
  gemm_k<2><<<dim3(64,4,1), blk, 0, stream>>>(hist, (ushort_t*)(ws+OFF_CTX),
                                              W3, b3, out, ws,
                                              512, 1024, 1024, 0, 0, 1, 0,0, 0L);
}